// Round 9
// baseline (274.401 us; speedup 1.0000x reference)
//
#include <hip/hip_runtime.h>
#include <hip/hip_fp16.h>
#include <cstdint>
#include <cstddef>

// OccupancyModel: feats = grid[round(clip(p*127))]  (2M x 16 gather)
//   h1 = relu(feats @ W1^T + b1); h2 = relu(h1 @ W2^T + b2); occ = tanh(h2 @ W3^T + b3)
//
// R15 == R14 with the prologue cslot fix. R14 failed absmax 0.286:
// `loadFeat(3, 3); loadFeat(4, 4)` passed cslot=3,4 into the 3-entry
// coords ring (Cx[3]/Cx[4] OOB -> garbage gather addresses for pairs 3,4
// = 4 of 16 tiles/wave wrong). Intended mapping is cslot = pair%3:
// loadFeat(3, 0) / loadFeat(4, 1). Full slot timeline re-traced: slot p%3
// holds pair p at every loadFeat site; all feat-slot consumes precede
// same-slot refills.
//
// R13: deeper cover + packed-f16 relu. R12 (91us) still latency-bound
// (Mfma 11 / VALU 40 / HBM 21, ~50% issue idle). VGPR 84 < live ~121,
// zero spill => state parked in AGPRs (unified file); occupancy (~28%)
// file-bound. Per-wave levers:
//   * feat ring 5 pairs, prefetch distance 5 = 10 tiles in flight.
//   * pk-relu (cvt_pkrtz + v_pk_max_f16), -24 VALU/tile; same u32 layout
//     into the verified shuffle network; layer 3 stays f32.
//   * W-A-R: distance == depth -> extract BOTH tiles' fragments (incl.
//     tile B's shfl_xor) before the same-slot refill (R8 lesson).
//
// R12: dual-tile full-lane gather (quads 0,1 load tile A's 64B cells,
// quads 2,3 tile B; tile B's fragment via 8 shfl_xor(.,32)).
//
// MLP core verified R1-R12 (absmax 1.95e-3): fp16 MFMA 16x16x32,
// H^T = W @ feats^T, points on n-dim (col=lane&15); b1 folded into the
// layer-1 K-pad slot; layer1->2 relayout via 16 cross-quad shuffles;
// tanh = 1 - 2/(exp(2x)+1).

typedef _Float16 half8 __attribute__((ext_vector_type(8)));
typedef __fp16  fp16v2 __attribute__((ext_vector_type(2)));
typedef float float4v __attribute__((ext_vector_type(4)));

#define WPB 4   // waves per block
#define NT  16  // tiles per wave (256 points)
#define NP  8   // tile-pairs per wave
#define FD  5   // feature ring depth (pairs); prefetch distance == FD

// relu in packed f16: 1x v_cvt_pkrtz_f16_f32 + 1x v_pk_max_f16
__device__ inline uint32_t relu_pk(float a, float b) {
    union { fp16v2 h; uint32_t u; } c;
    fp16v2 h = __builtin_amdgcn_cvt_pkrtz(a, b);
    fp16v2 z = {};
    c.h = __builtin_elementwise_max(h, z);
    return c.u;
}

__global__ __launch_bounds__(256, 3) void occ_mlp_kernel(
    const float* __restrict__ pts,
    const float* __restrict__ grid,
    const float* __restrict__ W1, const float* __restrict__ b1,
    const float* __restrict__ W2, const float* __restrict__ b2,
    const float* __restrict__ W3, const float* __restrict__ b3,
    float* __restrict__ out, int nPoints)
{
    const int lane = threadIdx.x & 63;
    const int l15  = lane & 15;
    const int quad = lane >> 4;
    const int wib  = threadIdx.x >> 6;
    const int tile0 = (blockIdx.x * WPB + wib) * NT;
    const int nTiles = (nPoints + 15) >> 4;
    if (tile0 >= nTiles) return;
    const int maxP = nPoints - 1;
    const int pt0  = tile0 << 4;

    // gather-lane mapping: quads 0,1 own tile A of the pair (halves 0,1 of
    // each point's 64B cell); quads 2,3 own tile B (halves 0,1).
    const int half = quad & 1;   // which 32B half of the cell this lane loads
    const int tsel = quad >> 1;  // 0 = tile A's points, 1 = tile B's points

    // ---- loop-invariant weight fragments ----
    // A layout: A[m = lane&15][k = quad*8 + j]. Layer1 K=16 padded to 32;
    // b1 folded at k=16 (quad2 j=0), bfrag's k=16 slot = 1.0.
    half8 A1[4];
#pragma unroll
    for (int t = 0; t < 4; ++t) {
        half8 f = {};
        if (quad < 2) {
            const float* row = W1 + (16 * t + l15) * 16 + quad * 8;
#pragma unroll
            for (int j = 0; j < 8; ++j) f[j] = (_Float16)row[j];
        } else if (quad == 2) {
            f[0] = (_Float16)b1[16 * t + l15];
        }
        A1[t] = f;
    }
    half8 A2[4][2];
#pragma unroll
    for (int t = 0; t < 4; ++t)
#pragma unroll
        for (int kk = 0; kk < 2; ++kk) {
            const float* row = W2 + (16 * t + l15) * 64 + 32 * kk + 8 * quad;
            half8 f;
#pragma unroll
            for (int j = 0; j < 8; ++j) f[j] = (_Float16)row[j];
            A2[t][kk] = f;
        }
    // C/D layout: col = lane&15 (point), row = quad*4 + reg.
    float4v bias2[4];
    float w3v[4][4];
#pragma unroll
    for (int t = 0; t < 4; ++t)
#pragma unroll
        for (int r = 0; r < 4; ++r) {
            int h = 16 * t + 4 * quad + r;
            bias2[t][r] = b2[h];
            w3v[t][r]   = W3[h];
        }
    const float bias3 = b3[0];

    // layer1->layer2 cross-quad shuffle plan
    const int src0 = l15 + 16 * ((2 * quad) & 3);
    const int src1 = l15 + 16 * ((2 * quad + 1) & 3);
    const bool sel = (quad >> 1) != 0;

    // ---- register pipeline state (pair-granular) ----
    // coords ring: 3 pairs deep; slot p%3 holds pair p's coords.
    float Cx[3], Cy[3], Cz[3];
    // feature ring: FD=5 pairs deep (10 tiles in flight).
    float4 Fa[FD], Fb[FD];

    auto loadCoords = [&](int slot, int v) {
        int p = pt0 + v * 32 + (tsel << 4) + l15;
        p = p > maxP ? maxP : p;
        const float* q = pts + 3 * p;
        Cx[slot] = q[0]; Cy[slot] = q[1]; Cz[slot] = q[2];
    };
    auto loadFeat = [&](int fslot, int cslot) {
        const int ix = (int)rintf(fminf(fmaxf(Cx[cslot] * 127.0f, 0.0f), 127.0f));
        const int iy = (int)rintf(fminf(fmaxf(Cy[cslot] * 127.0f, 0.0f), 127.0f));
        const int iz = (int)rintf(fminf(fmaxf(Cz[cslot] * 127.0f, 0.0f), 127.0f));
        const int ofs = ((((ix << 7) | iy) << 7) | iz) << 4;  // floats
        const float4* g = reinterpret_cast<const float4*>(grid + ofs + (half << 3));
        Fa[fslot] = g[0];
        Fb[fslot] = g[1];
    };

    // ---- prologue: feats f0..f4 + coords through pair 6 in flight ----
    loadCoords(0, 0); loadCoords(1, 1); loadCoords(2, 2);
    loadFeat(0, 0); loadFeat(1, 1); loadFeat(2, 2);
    loadCoords(0, 3); loadCoords(1, 4);
    loadFeat(3, 0); loadFeat(4, 1);      // pair3 <- slot0, pair4 <- slot1
    loadCoords(2, 5); loadCoords(0, 6);

    float o[4];

#pragma unroll
    for (int v = 0; v < NP; ++v) {
        const int s = v % FD;

        // ---- extract BOTH tiles' raw fragments from slot s FIRST ----
        // (refill below writes this same slot; all reads of Fa[s]/Fb[s] -
        // including tile B's shfl_xor - must precede it in program order.)
        const float4 a0 = Fa[s];
        const float4 a1 = Fb[s];
        float4 b0, b1v;
        b0.x  = __shfl_xor(Fa[s].x, 32); b0.y  = __shfl_xor(Fa[s].y, 32);
        b0.z  = __shfl_xor(Fa[s].z, 32); b0.w  = __shfl_xor(Fa[s].w, 32);
        b1v.x = __shfl_xor(Fb[s].x, 32); b1v.y = __shfl_xor(Fb[s].y, 32);
        b1v.z = __shfl_xor(Fb[s].z, 32); b1v.w = __shfl_xor(Fb[s].w, 32);

        // ---- refill pipeline (flies across this pair's compute) ----
        // feat pair v+FD's coords sit in slot (v+FD)%3 (loaded 2+ pairs ago);
        // coords pair v+7 -> slot (v+7)%3 (its old pair consumed already).
        if (v + FD < NP) loadFeat(s, (v + FD) % 3);
        if (v + 7  < NP) loadCoords((v + 7) % 3, v + 7);

#pragma unroll
        for (int tt = 0; tt < 2; ++tt) {
            const int u = 2 * v + tt;  // tile index within wave
            const float4 f0 = tt ? b0 : a0;
            const float4 f1 = tt ? b1v : a1;

            half8 bfrag = {};
            if (quad < 2) {
                bfrag[0] = (_Float16)f0.x; bfrag[1] = (_Float16)f0.y;
                bfrag[2] = (_Float16)f0.z; bfrag[3] = (_Float16)f0.w;
                bfrag[4] = (_Float16)f1.x; bfrag[5] = (_Float16)f1.y;
                bfrag[6] = (_Float16)f1.z; bfrag[7] = (_Float16)f1.w;
            } else if (quad == 2) {
                bfrag[0] = (_Float16)1.0f;  // multiplies the folded b1 column
            }

            // layer 1 (bias via folded K-slot)
            float4v C1[4];
#pragma unroll
            for (int t = 0; t < 4; ++t) {
                float4v zacc = {};
                C1[t] = __builtin_amdgcn_mfma_f32_16x16x32_f16(A1[t], bfrag, zacc, 0, 0, 0);
            }

            // relu + f16 pack: packed (cvt_pkrtz + pk_max), same u32 layout
            uint32_t P[4][2];
#pragma unroll
            for (int t = 0; t < 4; ++t) {
                P[t][0] = relu_pk(C1[t][0], C1[t][1]);
                P[t][1] = relu_pk(C1[t][2], C1[t][3]);
            }

            // cross-quad shuffle into layer-2 B fragments
            union Frag { uint32_t u[4]; half8 h; } B2[2];
#pragma unroll
            for (int kk = 0; kk < 2; ++kk) {
                const uint32_t x0a = (uint32_t)__shfl((int)P[2 * kk    ][0], src0);
                const uint32_t x0b = (uint32_t)__shfl((int)P[2 * kk + 1][0], src0);
                const uint32_t x1a = (uint32_t)__shfl((int)P[2 * kk    ][1], src0);
                const uint32_t x1b = (uint32_t)__shfl((int)P[2 * kk + 1][1], src0);
                const uint32_t y0a = (uint32_t)__shfl((int)P[2 * kk    ][0], src1);
                const uint32_t y0b = (uint32_t)__shfl((int)P[2 * kk + 1][0], src1);
                const uint32_t y1a = (uint32_t)__shfl((int)P[2 * kk    ][1], src1);
                const uint32_t y1b = (uint32_t)__shfl((int)P[2 * kk + 1][1], src1);
                B2[kk].u[0] = sel ? x0b : x0a;
                B2[kk].u[1] = sel ? x1b : x1a;
                B2[kk].u[2] = sel ? y0b : y0a;
                B2[kk].u[3] = sel ? y1b : y1a;
            }

            // layer 2 (bias as initial accumulator)
            float4v C2[4];
#pragma unroll
            for (int t = 0; t < 4; ++t) C2[t] = bias2[t];
#pragma unroll
            for (int kk = 0; kk < 2; ++kk)
#pragma unroll
                for (int t = 0; t < 4; ++t)
                    C2[t] = __builtin_amdgcn_mfma_f32_16x16x32_f16(A2[t][kk], B2[kk].h, C2[t], 0, 0, 0);

            // layer 3: dot(relu(h2), w3) in f32, reduce across quads
            float z = 0.0f;
#pragma unroll
            for (int t = 0; t < 4; ++t)
#pragma unroll
                for (int r = 0; r < 4; ++r)
                    z = fmaf(fmaxf(C2[t][r], 0.0f), w3v[t][r], z);
            z += __shfl_xor(z, 16);
            z += __shfl_xor(z, 32);
            const float e = __expf(2.0f * (z + bias3));
            o[u & 3] = fmaf(-2.0f, __builtin_amdgcn_rcpf(e + 1.0f), 1.0f);

            // every 4 tiles: one coalesced 256B store (64 points)
            if ((u & 3) == 3) {
                const float osel = (quad == 0) ? o[0] : (quad == 1) ? o[1]
                                 : (quad == 2) ? o[2] : o[3];
                const int pstore = (tile0 + (u & ~3)) * 16 + lane;
                if (pstore <= maxP) out[pstore] = osel;
            }
        }

        // pin the load schedule to the written pipeline depth: memory ops
        // cannot cross this fence; VALU/MFMA still schedule freely.
        asm volatile("" ::: "memory");
    }
}

extern "C" void kernel_launch(void* const* d_in, const int* in_sizes, int n_in,
                              void* d_out, int out_size, void* d_ws, size_t ws_size,
                              hipStream_t stream)
{
    const float* pts  = (const float*)d_in[0];
    const float* grid = (const float*)d_in[1];
    const float* W1   = (const float*)d_in[2];
    const float* b1   = (const float*)d_in[3];
    const float* W2   = (const float*)d_in[4];
    const float* b2   = (const float*)d_in[5];
    const float* W3   = (const float*)d_in[6];
    const float* b3   = (const float*)d_in[7];
    float* out = (float*)d_out;
    const int nPoints = in_sizes[0] / 3;

    const int nTiles = (nPoints + 15) >> 4;
    const int tilesPerBlock = WPB * NT;              // 64
    const int nBlocks = (nTiles + tilesPerBlock - 1) / tilesPerBlock;  // 2048

    occ_mlp_kernel<<<dim3(nBlocks), dim3(256), 0, stream>>>(
        pts, grid, W1, b1, W2, b2, W3, b3, out, nPoints);
}

// Round 10
// 253.771 us; speedup vs baseline: 1.0813x; 1.0813x over previous
//
#include <hip/hip_runtime.h>
#include <hip/hip_fp16.h>
#include <cstdint>
#include <cstddef>

// OccupancyModel: feats = grid[round(clip(p*127))]  (2M x 16 gather)
//   h1 = relu(feats @ W1^T + b1); h2 = relu(h1 @ W2^T + b2); occ = tanh(h2 @ W3^T + b3)
//
// R16 == R15 with ONE token changed: __launch_bounds__(256, 3) -> (256, 2).
// R15 passed correctness (absmax 1.95e-3) but spilled: WRITE_SIZE 8->59MB
// (51MB scratch), FETCH +26MB, dur 117us. FD=5 added 16 regs to a state
// already at the (256,3) unified cap (~170) -> allocator dumped to scratch.
// (256,2) raises the cap to 256; the verified FD=5 pipeline (~190 live incl
// transients) fits. Occupancy 2.25 -> 2 waves/SIMD (negligible), spill gone,
// and the deeper in-flight window actually materializes.
//
// Why depth: Little's law on the 2M x 64B random gather. R10->R11->R12
// scaled per-wave in-flight 2->4->6KB; measured gather BW 1.30->1.45->1.67
// TB/s, dur 116->105->91us. Latency/MLP-bound; per-CU outstanding bytes is
// the binding resource. FD=5 (distance 5 pairs = 10KB/wave) -> ~80KB/CU.
//
// R15: prologue cslot fix (R14 passed cslot=3,4 into the 3-entry coords
// ring -> OOB garbage for pairs 3,4). Slot rule: coords slot p%3 holds
// pair p at every loadFeat site; feat-slot consumes precede same-slot
// refills (R8 lesson: extract BOTH tiles' fragments incl. shfl_xor first).
//
// R13: pk-relu (cvt_pkrtz + v_pk_max_f16), -24 VALU/tile, same u32 layout
// into the verified shuffle network; layer 3 stays f32.
// R12: dual-tile full-lane gather (quads 0,1 load tile A's 64B cells,
// quads 2,3 tile B; tile B's fragment via 8 shfl_xor(.,32)).
//
// MLP core verified R1-R15 (absmax 1.95e-3): fp16 MFMA 16x16x32,
// H^T = W @ feats^T, points on n-dim (col=lane&15); b1 folded into the
// layer-1 K-pad slot; layer1->2 relayout via 16 cross-quad shuffles;
// tanh = 1 - 2/(exp(2x)+1).

typedef _Float16 half8 __attribute__((ext_vector_type(8)));
typedef __fp16  fp16v2 __attribute__((ext_vector_type(2)));
typedef float float4v __attribute__((ext_vector_type(4)));

#define WPB 4   // waves per block
#define NT  16  // tiles per wave (256 points)
#define NP  8   // tile-pairs per wave
#define FD  5   // feature ring depth (pairs); prefetch distance == FD

// relu in packed f16: 1x v_cvt_pkrtz_f16_f32 + 1x v_pk_max_f16
__device__ inline uint32_t relu_pk(float a, float b) {
    union { fp16v2 h; uint32_t u; } c;
    fp16v2 h = __builtin_amdgcn_cvt_pkrtz(a, b);
    fp16v2 z = {};
    c.h = __builtin_elementwise_max(h, z);
    return c.u;
}

__global__ __launch_bounds__(256, 2) void occ_mlp_kernel(
    const float* __restrict__ pts,
    const float* __restrict__ grid,
    const float* __restrict__ W1, const float* __restrict__ b1,
    const float* __restrict__ W2, const float* __restrict__ b2,
    const float* __restrict__ W3, const float* __restrict__ b3,
    float* __restrict__ out, int nPoints)
{
    const int lane = threadIdx.x & 63;
    const int l15  = lane & 15;
    const int quad = lane >> 4;
    const int wib  = threadIdx.x >> 6;
    const int tile0 = (blockIdx.x * WPB + wib) * NT;
    const int nTiles = (nPoints + 15) >> 4;
    if (tile0 >= nTiles) return;
    const int maxP = nPoints - 1;
    const int pt0  = tile0 << 4;

    // gather-lane mapping: quads 0,1 own tile A of the pair (halves 0,1 of
    // each point's 64B cell); quads 2,3 own tile B (halves 0,1).
    const int half = quad & 1;   // which 32B half of the cell this lane loads
    const int tsel = quad >> 1;  // 0 = tile A's points, 1 = tile B's points

    // ---- loop-invariant weight fragments ----
    // A layout: A[m = lane&15][k = quad*8 + j]. Layer1 K=16 padded to 32;
    // b1 folded at k=16 (quad2 j=0), bfrag's k=16 slot = 1.0.
    half8 A1[4];
#pragma unroll
    for (int t = 0; t < 4; ++t) {
        half8 f = {};
        if (quad < 2) {
            const float* row = W1 + (16 * t + l15) * 16 + quad * 8;
#pragma unroll
            for (int j = 0; j < 8; ++j) f[j] = (_Float16)row[j];
        } else if (quad == 2) {
            f[0] = (_Float16)b1[16 * t + l15];
        }
        A1[t] = f;
    }
    half8 A2[4][2];
#pragma unroll
    for (int t = 0; t < 4; ++t)
#pragma unroll
        for (int kk = 0; kk < 2; ++kk) {
            const float* row = W2 + (16 * t + l15) * 64 + 32 * kk + 8 * quad;
            half8 f;
#pragma unroll
            for (int j = 0; j < 8; ++j) f[j] = (_Float16)row[j];
            A2[t][kk] = f;
        }
    // C/D layout: col = lane&15 (point), row = quad*4 + reg.
    float4v bias2[4];
    float w3v[4][4];
#pragma unroll
    for (int t = 0; t < 4; ++t)
#pragma unroll
        for (int r = 0; r < 4; ++r) {
            int h = 16 * t + 4 * quad + r;
            bias2[t][r] = b2[h];
            w3v[t][r]   = W3[h];
        }
    const float bias3 = b3[0];

    // layer1->layer2 cross-quad shuffle plan
    const int src0 = l15 + 16 * ((2 * quad) & 3);
    const int src1 = l15 + 16 * ((2 * quad + 1) & 3);
    const bool sel = (quad >> 1) != 0;

    // ---- register pipeline state (pair-granular) ----
    // coords ring: 3 pairs deep; slot p%3 holds pair p's coords.
    float Cx[3], Cy[3], Cz[3];
    // feature ring: FD=5 pairs deep (10 tiles in flight).
    float4 Fa[FD], Fb[FD];

    auto loadCoords = [&](int slot, int v) {
        int p = pt0 + v * 32 + (tsel << 4) + l15;
        p = p > maxP ? maxP : p;
        const float* q = pts + 3 * p;
        Cx[slot] = q[0]; Cy[slot] = q[1]; Cz[slot] = q[2];
    };
    auto loadFeat = [&](int fslot, int cslot) {
        const int ix = (int)rintf(fminf(fmaxf(Cx[cslot] * 127.0f, 0.0f), 127.0f));
        const int iy = (int)rintf(fminf(fmaxf(Cy[cslot] * 127.0f, 0.0f), 127.0f));
        const int iz = (int)rintf(fminf(fmaxf(Cz[cslot] * 127.0f, 0.0f), 127.0f));
        const int ofs = ((((ix << 7) | iy) << 7) | iz) << 4;  // floats
        const float4* g = reinterpret_cast<const float4*>(grid + ofs + (half << 3));
        Fa[fslot] = g[0];
        Fb[fslot] = g[1];
    };

    // ---- prologue: feats f0..f4 + coords through pair 6 in flight ----
    loadCoords(0, 0); loadCoords(1, 1); loadCoords(2, 2);
    loadFeat(0, 0); loadFeat(1, 1); loadFeat(2, 2);
    loadCoords(0, 3); loadCoords(1, 4);
    loadFeat(3, 0); loadFeat(4, 1);      // pair3 <- slot0, pair4 <- slot1
    loadCoords(2, 5); loadCoords(0, 6);

    float o[4];

#pragma unroll
    for (int v = 0; v < NP; ++v) {
        const int s = v % FD;

        // ---- extract BOTH tiles' raw fragments from slot s FIRST ----
        // (refill below writes this same slot; all reads of Fa[s]/Fb[s] -
        // including tile B's shfl_xor - must precede it in program order.)
        const float4 a0 = Fa[s];
        const float4 a1 = Fb[s];
        float4 b0, b1v;
        b0.x  = __shfl_xor(Fa[s].x, 32); b0.y  = __shfl_xor(Fa[s].y, 32);
        b0.z  = __shfl_xor(Fa[s].z, 32); b0.w  = __shfl_xor(Fa[s].w, 32);
        b1v.x = __shfl_xor(Fb[s].x, 32); b1v.y = __shfl_xor(Fb[s].y, 32);
        b1v.z = __shfl_xor(Fb[s].z, 32); b1v.w = __shfl_xor(Fb[s].w, 32);

        // ---- refill pipeline (flies across this pair's compute) ----
        // feat pair v+FD's coords sit in slot (v+FD)%3 (loaded 2+ pairs ago);
        // coords pair v+7 -> slot (v+7)%3 (its old pair consumed already).
        if (v + FD < NP) loadFeat(s, (v + FD) % 3);
        if (v + 7  < NP) loadCoords((v + 7) % 3, v + 7);

#pragma unroll
        for (int tt = 0; tt < 2; ++tt) {
            const int u = 2 * v + tt;  // tile index within wave
            const float4 f0 = tt ? b0 : a0;
            const float4 f1 = tt ? b1v : a1;

            half8 bfrag = {};
            if (quad < 2) {
                bfrag[0] = (_Float16)f0.x; bfrag[1] = (_Float16)f0.y;
                bfrag[2] = (_Float16)f0.z; bfrag[3] = (_Float16)f0.w;
                bfrag[4] = (_Float16)f1.x; bfrag[5] = (_Float16)f1.y;
                bfrag[6] = (_Float16)f1.z; bfrag[7] = (_Float16)f1.w;
            } else if (quad == 2) {
                bfrag[0] = (_Float16)1.0f;  // multiplies the folded b1 column
            }

            // layer 1 (bias via folded K-slot)
            float4v C1[4];
#pragma unroll
            for (int t = 0; t < 4; ++t) {
                float4v zacc = {};
                C1[t] = __builtin_amdgcn_mfma_f32_16x16x32_f16(A1[t], bfrag, zacc, 0, 0, 0);
            }

            // relu + f16 pack: packed (cvt_pkrtz + pk_max), same u32 layout
            uint32_t P[4][2];
#pragma unroll
            for (int t = 0; t < 4; ++t) {
                P[t][0] = relu_pk(C1[t][0], C1[t][1]);
                P[t][1] = relu_pk(C1[t][2], C1[t][3]);
            }

            // cross-quad shuffle into layer-2 B fragments
            union Frag { uint32_t u[4]; half8 h; } B2[2];
#pragma unroll
            for (int kk = 0; kk < 2; ++kk) {
                const uint32_t x0a = (uint32_t)__shfl((int)P[2 * kk    ][0], src0);
                const uint32_t x0b = (uint32_t)__shfl((int)P[2 * kk + 1][0], src0);
                const uint32_t x1a = (uint32_t)__shfl((int)P[2 * kk    ][1], src0);
                const uint32_t x1b = (uint32_t)__shfl((int)P[2 * kk + 1][1], src0);
                const uint32_t y0a = (uint32_t)__shfl((int)P[2 * kk    ][0], src1);
                const uint32_t y0b = (uint32_t)__shfl((int)P[2 * kk + 1][0], src1);
                const uint32_t y1a = (uint32_t)__shfl((int)P[2 * kk    ][1], src1);
                const uint32_t y1b = (uint32_t)__shfl((int)P[2 * kk + 1][1], src1);
                B2[kk].u[0] = sel ? x0b : x0a;
                B2[kk].u[1] = sel ? x1b : x1a;
                B2[kk].u[2] = sel ? y0b : y0a;
                B2[kk].u[3] = sel ? y1b : y1a;
            }

            // layer 2 (bias as initial accumulator)
            float4v C2[4];
#pragma unroll
            for (int t = 0; t < 4; ++t) C2[t] = bias2[t];
#pragma unroll
            for (int kk = 0; kk < 2; ++kk)
#pragma unroll
                for (int t = 0; t < 4; ++t)
                    C2[t] = __builtin_amdgcn_mfma_f32_16x16x32_f16(A2[t][kk], B2[kk].h, C2[t], 0, 0, 0);

            // layer 3: dot(relu(h2), w3) in f32, reduce across quads
            float z = 0.0f;
#pragma unroll
            for (int t = 0; t < 4; ++t)
#pragma unroll
                for (int r = 0; r < 4; ++r)
                    z = fmaf(fmaxf(C2[t][r], 0.0f), w3v[t][r], z);
            z += __shfl_xor(z, 16);
            z += __shfl_xor(z, 32);
            const float e = __expf(2.0f * (z + bias3));
            o[u & 3] = fmaf(-2.0f, __builtin_amdgcn_rcpf(e + 1.0f), 1.0f);

            // every 4 tiles: one coalesced 256B store (64 points)
            if ((u & 3) == 3) {
                const float osel = (quad == 0) ? o[0] : (quad == 1) ? o[1]
                                 : (quad == 2) ? o[2] : o[3];
                const int pstore = (tile0 + (u & ~3)) * 16 + lane;
                if (pstore <= maxP) out[pstore] = osel;
            }
        }

        // pin the load schedule to the written pipeline depth: memory ops
        // cannot cross this fence; VALU/MFMA still schedule freely.
        asm volatile("" ::: "memory");
    }
}

extern "C" void kernel_launch(void* const* d_in, const int* in_sizes, int n_in,
                              void* d_out, int out_size, void* d_ws, size_t ws_size,
                              hipStream_t stream)
{
    const float* pts  = (const float*)d_in[0];
    const float* grid = (const float*)d_in[1];
    const float* W1   = (const float*)d_in[2];
    const float* b1   = (const float*)d_in[3];
    const float* W2   = (const float*)d_in[4];
    const float* b2   = (const float*)d_in[5];
    const float* W3   = (const float*)d_in[6];
    const float* b3   = (const float*)d_in[7];
    float* out = (float*)d_out;
    const int nPoints = in_sizes[0] / 3;

    const int nTiles = (nPoints + 15) >> 4;
    const int tilesPerBlock = WPB * NT;              // 64
    const int nBlocks = (nTiles + tilesPerBlock - 1) / tilesPerBlock;  // 2048

    occ_mlp_kernel<<<dim3(nBlocks), dim3(256), 0, stream>>>(
        pts, grid, W1, b1, W2, b2, W3, b3, out, nPoints);
}

// Round 11
// 239.487 us; speedup vs baseline: 1.1458x; 1.0596x over previous
//
#include <hip/hip_runtime.h>
#include <hip/hip_fp16.h>
#include <cstdint>
#include <cstddef>

// OccupancyModel: feats = grid[round(clip(p*127))]  (2M x 16 gather)
//   h1 = relu(feats @ W1^T + b1); h2 = relu(h1 @ W2^T + b2); occ = tanh(h2 @ W3^T + b3)
//
// R17: weights -> LDS to buy residency. Model (fits R6,R9-R16): residency
// = 2048 unified regs / (VGPR+AGPR per wave). Compiler parks the ~80 regs
// of loop-invariant weights in AGPRs (why VGPR_Count 84-96 << live ~230),
// so every wave redundantly holds block-uniform data -> ~9 waves/CU, each
// memory-stalled ~75% with nobody to cover (VALU 40% at 2.25 waves/SIMD).
// Depth and occupancy traded on an iso-line (R12 91us @28% vs R16 94.7us
// @20.6%). HBM traffic is already exactly compulsory (140MB = 114MB grid
// lines [1-e^-2 model] + 24MB pts). So: share A1/A2 via LDS (12KB/block),
// ds_read_b128 per tile; frag id = t*64+lane -> dense-sequential 16B/lane
// = conflict-free. Per-iteration asm fence blocks LICM re-hoisting the
// reads into registers. -48 unified regs/wave -> ~11+ waves/CU.
//
// Ring schedule = R12's proven indices (4-pair feat ring, distance 3, no
// same-slot hazard; coords slot p%3). pk-relu kept (green in R15/R16).
// One __syncthreads in prologue only; 2048x64 tiles divides 131072 exactly
// so every wave reaches it.
//
// R12: dual-tile full-lane gather (quads 0,1 load tile A's 64B cells,
// quads 2,3 tile B; tile B's fragment via 8 shfl_xor(.,32)).
//
// MLP core verified R1-R16 (absmax 1.95e-3): fp16 MFMA 16x16x32,
// H^T = W @ feats^T, points on n-dim (col=lane&15); b1 folded into the
// layer-1 K-pad slot; layer1->2 relayout via 16 cross-quad shuffles;
// tanh = 1 - 2/(exp(2x)+1).

typedef _Float16 half8 __attribute__((ext_vector_type(8)));
typedef __fp16  fp16v2 __attribute__((ext_vector_type(2)));
typedef float float4v __attribute__((ext_vector_type(4)));

#define WPB 4   // waves per block
#define NT  16  // tiles per wave (256 points)
#define NP  8   // tile-pairs per wave

// relu in packed f16: 1x v_cvt_pkrtz_f16_f32 + 1x v_pk_max_f16
__device__ inline uint32_t relu_pk(float a, float b) {
    union { fp16v2 h; uint32_t u; } c;
    fp16v2 h = __builtin_amdgcn_cvt_pkrtz(a, b);
    fp16v2 z = {};
    c.h = __builtin_elementwise_max(h, z);
    return c.u;
}

__global__ __launch_bounds__(256, 3) void occ_mlp_kernel(
    const float* __restrict__ pts,
    const float* __restrict__ grid,
    const float* __restrict__ W1, const float* __restrict__ b1,
    const float* __restrict__ W2, const float* __restrict__ b2,
    const float* __restrict__ W3, const float* __restrict__ b3,
    float* __restrict__ out, int nPoints)
{
    // shared weight fragments: [0..255] A1 (t*64+lane), [256..767] A2
    // ((t*2+kk)*64+lane). 768 x 16B = 12KB.
    __shared__ half8 wlds[768];

    const int lane = threadIdx.x & 63;
    const int l15  = lane & 15;
    const int quad = lane >> 4;
    const int wib  = threadIdx.x >> 6;
    const int tile0 = (blockIdx.x * WPB + wib) * NT;
    const int nTiles = (nPoints + 15) >> 4;
    const int maxP = nPoints - 1;
    const int pt0  = tile0 << 4;

    // ---- stage weight fragments to LDS (wave wib builds t = wib) ----
    {
        const int t = wib;
        half8 f = {};
        if (quad < 2) {
            const float* row = W1 + (16 * t + l15) * 16 + quad * 8;
#pragma unroll
            for (int j = 0; j < 8; ++j) f[j] = (_Float16)row[j];
        } else if (quad == 2) {
            f[0] = (_Float16)b1[16 * t + l15];   // folded b1 column (k=16)
        }
        wlds[t * 64 + lane] = f;
#pragma unroll
        for (int kk = 0; kk < 2; ++kk) {
            const float* row = W2 + (16 * t + l15) * 64 + 32 * kk + 8 * quad;
            half8 g;
#pragma unroll
            for (int j = 0; j < 8; ++j) g[j] = (_Float16)row[j];
            wlds[256 + (t * 2 + kk) * 64 + lane] = g;
        }
    }
    __syncthreads();
    if (tile0 >= nTiles) return;   // never taken (exact division); after barrier for safety

    // gather-lane mapping: quads 0,1 own tile A of the pair (halves 0,1 of
    // each point's 64B cell); quads 2,3 own tile B (halves 0,1).
    const int half = quad & 1;   // which 32B half of the cell this lane loads
    const int tsel = quad >> 1;  // 0 = tile A's points, 1 = tile B's points

    // small per-lane constants kept in regs (32 regs): layer-2 bias + W3.
    // C/D layout: col = lane&15 (point), row = quad*4 + reg.
    float4v bias2[4];
    float w3v[4][4];
#pragma unroll
    for (int t = 0; t < 4; ++t)
#pragma unroll
        for (int r = 0; r < 4; ++r) {
            int h = 16 * t + 4 * quad + r;
            bias2[t][r] = b2[h];
            w3v[t][r]   = W3[h];
        }
    const float bias3 = b3[0];

    // layer1->layer2 cross-quad shuffle plan
    const int src0 = l15 + 16 * ((2 * quad) & 3);
    const int src1 = l15 + 16 * ((2 * quad + 1) & 3);
    const bool sel = (quad >> 1) != 0;

    // ---- register pipeline state (pair-granular, R12 schedule) ----
    // coords ring: 3 pairs deep; slot p%3 holds pair p's coords.
    float Cx[3], Cy[3], Cz[3];
    // feature ring: 4 pairs deep (8 tiles in flight), distance 3.
    float4 Fa[4], Fb[4];

    auto loadCoords = [&](int slot, int v) {
        int p = pt0 + v * 32 + (tsel << 4) + l15;
        p = p > maxP ? maxP : p;
        const float* q = pts + 3 * p;
        Cx[slot] = q[0]; Cy[slot] = q[1]; Cz[slot] = q[2];
    };
    auto loadFeat = [&](int fslot, int cslot) {
        const int ix = (int)rintf(fminf(fmaxf(Cx[cslot] * 127.0f, 0.0f), 127.0f));
        const int iy = (int)rintf(fminf(fmaxf(Cy[cslot] * 127.0f, 0.0f), 127.0f));
        const int iz = (int)rintf(fminf(fmaxf(Cz[cslot] * 127.0f, 0.0f), 127.0f));
        const int ofs = ((((ix << 7) | iy) << 7) | iz) << 4;  // floats
        const float4* g = reinterpret_cast<const float4*>(grid + ofs + (half << 3));
        Fa[fslot] = g[0];
        Fb[fslot] = g[1];
    };

    // ---- prologue (R12): coords pairs 0-4, feats pairs 0-2 in flight ----
    loadCoords(0, 0); loadCoords(1, 1); loadCoords(2, 2);
    loadFeat(0, 0); loadFeat(1, 1); loadFeat(2, 2);
    loadCoords(0, 3); loadCoords(1, 4);

    float o[4];

#pragma unroll
    for (int v = 0; v < NP; ++v) {
        const int s = v & 3;

        // ---- extract BOTH tiles' raw fragments from slot s FIRST ----
        const float4 a0 = Fa[s];
        const float4 a1 = Fb[s];
        float4 b0, b1v;
        b0.x  = __shfl_xor(Fa[s].x, 32); b0.y  = __shfl_xor(Fa[s].y, 32);
        b0.z  = __shfl_xor(Fa[s].z, 32); b0.w  = __shfl_xor(Fa[s].w, 32);
        b1v.x = __shfl_xor(Fb[s].x, 32); b1v.y = __shfl_xor(Fb[s].y, 32);
        b1v.z = __shfl_xor(Fb[s].z, 32); b1v.w = __shfl_xor(Fb[s].w, 32);

        // ---- refill (R12 indices): feat pair v+3 -> slot (v+3)&3 != s;
        // its coords sit in slot (v+3)%3; coords pair v+5 -> slot (v+2)%3.
        if (v + 3 < NP) loadFeat((v + 3) & 3, v % 3);
        if (v + 5 < NP) loadCoords((v + 2) % 3, v + 5);

#pragma unroll
        for (int tt = 0; tt < 2; ++tt) {
            const int u = 2 * v + tt;  // tile index within wave
            const float4 f0 = tt ? b0 : a0;
            const float4 f1 = tt ? b1v : a1;

            half8 bfrag = {};
            if (quad < 2) {
                bfrag[0] = (_Float16)f0.x; bfrag[1] = (_Float16)f0.y;
                bfrag[2] = (_Float16)f0.z; bfrag[3] = (_Float16)f0.w;
                bfrag[4] = (_Float16)f1.x; bfrag[5] = (_Float16)f1.y;
                bfrag[6] = (_Float16)f1.z; bfrag[7] = (_Float16)f1.w;
            } else if (quad == 2) {
                bfrag[0] = (_Float16)1.0f;  // multiplies the folded b1 column
            }

            // layer 1 (A1 frags from LDS; bias via folded K-slot) + pk-relu
            uint32_t P[4][2];
#pragma unroll
            for (int t = 0; t < 4; ++t) {
                const half8 a1f = wlds[t * 64 + lane];
                float4v zacc = {};
                const float4v C1 = __builtin_amdgcn_mfma_f32_16x16x32_f16(a1f, bfrag, zacc, 0, 0, 0);
                P[t][0] = relu_pk(C1[0], C1[1]);
                P[t][1] = relu_pk(C1[2], C1[3]);
            }

            // cross-quad shuffle into layer-2 B fragments
            union Frag { uint32_t u[4]; half8 h; } B2[2];
#pragma unroll
            for (int kk = 0; kk < 2; ++kk) {
                const uint32_t x0a = (uint32_t)__shfl((int)P[2 * kk    ][0], src0);
                const uint32_t x0b = (uint32_t)__shfl((int)P[2 * kk + 1][0], src0);
                const uint32_t x1a = (uint32_t)__shfl((int)P[2 * kk    ][1], src0);
                const uint32_t x1b = (uint32_t)__shfl((int)P[2 * kk + 1][1], src0);
                const uint32_t y0a = (uint32_t)__shfl((int)P[2 * kk    ][0], src1);
                const uint32_t y0b = (uint32_t)__shfl((int)P[2 * kk + 1][0], src1);
                const uint32_t y1a = (uint32_t)__shfl((int)P[2 * kk    ][1], src1);
                const uint32_t y1b = (uint32_t)__shfl((int)P[2 * kk + 1][1], src1);
                B2[kk].u[0] = sel ? x0b : x0a;
                B2[kk].u[1] = sel ? x1b : x1a;
                B2[kk].u[2] = sel ? y0b : y0a;
                B2[kk].u[3] = sel ? y1b : y1a;
            }

            // layer 2 (A2 frags from LDS; bias as initial accumulator)
            float4v C2[4];
#pragma unroll
            for (int t = 0; t < 4; ++t) C2[t] = bias2[t];
#pragma unroll
            for (int kk = 0; kk < 2; ++kk)
#pragma unroll
                for (int t = 0; t < 4; ++t) {
                    const half8 a2f = wlds[256 + (t * 2 + kk) * 64 + lane];
                    C2[t] = __builtin_amdgcn_mfma_f32_16x16x32_f16(a2f, B2[kk].h, C2[t], 0, 0, 0);
                }

            // layer 3: dot(relu(h2), w3) in f32, reduce across quads
            float z = 0.0f;
#pragma unroll
            for (int t = 0; t < 4; ++t)
#pragma unroll
                for (int r = 0; r < 4; ++r)
                    z = fmaf(fmaxf(C2[t][r], 0.0f), w3v[t][r], z);
            z += __shfl_xor(z, 16);
            z += __shfl_xor(z, 32);
            const float e = __expf(2.0f * (z + bias3));
            o[u & 3] = fmaf(-2.0f, __builtin_amdgcn_rcpf(e + 1.0f), 1.0f);

            // every 4 tiles: one coalesced 256B store (64 points)
            if ((u & 3) == 3) {
                const float osel = (quad == 0) ? o[0] : (quad == 1) ? o[1]
                                 : (quad == 2) ? o[2] : o[3];
                const int pstore = (tile0 + (u & ~3)) * 16 + lane;
                if (pstore <= maxP) out[pstore] = osel;
            }
        }

        // pin the load schedule to the written pipeline depth; also stops
        // LICM from hoisting the LDS weight reads back into registers.
        asm volatile("" ::: "memory");
    }
}

extern "C" void kernel_launch(void* const* d_in, const int* in_sizes, int n_in,
                              void* d_out, int out_size, void* d_ws, size_t ws_size,
                              hipStream_t stream)
{
    const float* pts  = (const float*)d_in[0];
    const float* grid = (const float*)d_in[1];
    const float* W1   = (const float*)d_in[2];
    const float* b1   = (const float*)d_in[3];
    const float* W2   = (const float*)d_in[4];
    const float* b2   = (const float*)d_in[5];
    const float* W3   = (const float*)d_in[6];
    const float* b3   = (const float*)d_in[7];
    float* out = (float*)d_out;
    const int nPoints = in_sizes[0] / 3;

    const int nTiles = (nPoints + 15) >> 4;
    const int tilesPerBlock = WPB * NT;              // 64
    const int nBlocks = (nTiles + tilesPerBlock - 1) / tilesPerBlock;  // 2048

    occ_mlp_kernel<<<dim3(nBlocks), dim3(256), 0, stream>>>(
        pts, grid, W1, b1, W2, b2, W3, b3, out, nPoints);
}